// Round 8
// baseline (64.094 us; speedup 1.0000x reference)
//
#include <hip/hip_runtime.h>
#include <hip/hip_bf16.h>

#define NB 64
#define NN 512
#define CI 32
#define CO 64
#define XN 68
#define YR 80   // Yext rows per batch: 64 Y + mc + dg + 14 zero-pad

typedef __attribute__((ext_vector_type(8))) short bf16x8;
typedef __attribute__((ext_vector_type(4))) float f32x4;

__device__ inline short f2bf(float f) {
  union { __hip_bfloat16 h; unsigned short u; } cv;
  cv.h = __float2bfloat16(f);
  return (short)cv.u;
}

__device__ inline bf16x8 cvt8(float4 a, float4 b) {
  bf16x8 r;
  r[0] = f2bf(a.x); r[1] = f2bf(a.y); r[2] = f2bf(a.z); r[3] = f2bf(a.w);
  r[4] = f2bf(b.x); r[5] = f2bf(b.y); r[6] = f2bf(b.z); r[7] = f2bf(b.w);
  return r;
}

__device__ inline bf16x8 cvt8s(float4 a, float4 b, float s) {
  bf16x8 r;
  r[0] = f2bf(a.x * s); r[1] = f2bf(a.y * s); r[2] = f2bf(a.z * s); r[3] = f2bf(a.w * s);
  r[4] = f2bf(b.x * s); r[5] = f2bf(b.y * s); r[6] = f2bf(b.z * s); r[7] = f2bf(b.w * s);
  return r;
}

// ---------------- K1X: A row stats + X stats + Y-chunk (bf16 MFMA). grid (NB,32) ----------------
__global__ __launch_bounds__(256) void k1x(
    const float* __restrict__ A, const float* __restrict__ X,
    const float* __restrict__ cf, const float* __restrict__ W1,
    float* __restrict__ mc, float* __restrict__ dg, float* __restrict__ vec,
    float* __restrict__ pA, float* __restrict__ pD,
    float* __restrict__ pmX, float* __restrict__ ptC, float* __restrict__ pS,
    unsigned short* __restrict__ Yext) {
  int b = blockIdx.x, ch = blockIdx.y;
  int t = threadIdx.x, w = t >> 6, lane = t & 63;
  int r0 = ch * 16;
  const float* Ab = A + (size_t)b * NN * NN;
  __shared__ float sXc[16][33];
  __shared__ float scf[69];
  __shared__ float sMc[16], sDg[16], sVec[16], wsum[4];

  if (t < 69) scf[t] = cf[t];
  {  // stage X chunk: 16 rows x 32 cols
    int j = t >> 4, c = (t & 15) * 2;
    float2 xv = *(const float2*)(X + ((size_t)b * NN + r0 + j) * CI + c);
    sXc[j][c] = xv.x; sXc[j][c + 1] = xv.y;
  }
  float4 v0[4], v1[4];
#pragma unroll
  for (int m = 0; m < 4; ++m) {
    const float* rp = Ab + (size_t)(r0 + w * 4 + m) * NN;
    v0[m] = *(const float4*)(rp + lane * 4);
    v1[m] = *(const float4*)(rp + 256 + lane * 4);
  }
  float accR = 0.f;
#pragma unroll
  for (int m = 0; m < 4; ++m) {
    float s = (v0[m].x + v0[m].y) + (v0[m].z + v0[m].w) +
              (v1[m].x + v1[m].y) + (v1[m].z + v1[m].w);
#pragma unroll
    for (int off = 1; off < 64; off <<= 1) s += __shfl_xor(s, off, 64);
    if (lane == 0) {
      float m_ = s * (1.0f / NN);
      mc[b * NN + r0 + w * 4 + m] = m_;
      sMc[w * 4 + m] = m_;
    }
    accR += s;
  }
  if (lane == 0) wsum[w] = accR;
  if (t < 16) {
    float d = Ab[(size_t)(r0 + t) * NN + r0 + t];
    dg[b * NN + r0 + t] = d;
    sDg[t] = d;
  }
  __syncthreads();  // sXc, sMc, sDg, wsum, scf ready

  if (t < 16) {  // vec for this chunk's 16 rows
    float u = 0.f;
#pragma unroll
    for (int c = 0; c < CI; ++c) u += scf[5 + c] * sXc[t][c];
    float vj = scf[3] * sMc[t] + scf[4] * sDg[t] + u;
    vec[b * NN + r0 + t] = vj;
    sVec[t] = vj;
  } else if (t == 16) {
    pA[b * 32 + ch] = wsum[0] + wsum[1] + wsum[2] + wsum[3];
    float sd = 0.f;
#pragma unroll
    for (int k = 0; k < 16; ++k) sd += sDg[k];
    pD[b * 32 + ch] = sd;
  }

  {  // Y chunk via MFMA: wave w -> output rows o = w*16..w*16+15, cols r0..r0+15
    int ra = lane & 15, kg = lane >> 4, g = lane >> 4;
    const float* wp = W1 + (w * 16 + ra) * XN + kg * 8;
    bf16x8 wf = cvt8(*(const float4*)wp, *(const float4*)(wp + 4));
    const float* xp = &sXc[ra][kg * 8];
    bf16x8 xf = cvt8(*(const float4*)xp, *(const float4*)(xp + 4));
    f32x4 zero = {0.f, 0.f, 0.f, 0.f};
    f32x4 d = __builtin_amdgcn_mfma_f32_16x16x32_bf16(xf, wf, zero, 0, 0, 0);
    union { unsigned short u[4]; uint2 v; } pk;
#pragma unroll
    for (int r = 0; r < 4; ++r) pk.u[r] = (unsigned short)f2bf(d[r]);
    *(uint2*)(Yext + ((size_t)b * YR + w * 16 + ra) * NN + r0 + g * 4) = pk.v;
  }
  // Yext rows 64 (mc), 65 (dg) + zero pads 66..79, this chunk's 16 cols
  if (t < 16) {
    Yext[((size_t)b * YR + 64) * NN + r0 + t] = (unsigned short)f2bf(sMc[t]);
  } else if (t < 32) {
    Yext[((size_t)b * YR + 65) * NN + r0 + (t - 16)] = (unsigned short)f2bf(sDg[t - 16]);
  } else if (t < 32 + 224) {
    int u2 = t - 32;
    int row = 66 + (u2 >> 4), col = r0 + (u2 & 15);
    Yext[((size_t)b * YR + row) * NN + col] = 0;
  }
  __syncthreads();  // sVec ready

  if (t < 32) {  // column partials over this chunk
    float s1 = 0.f, s2 = 0.f;
#pragma unroll
    for (int r = 0; r < 16; ++r) {
      float xv = sXc[r][t];
      s1 += xv;
      s2 += sVec[r] * xv;
    }
    pmX[((size_t)b * 32 + ch) * 32 + t] = s1;
    ptC[((size_t)b * 32 + ch) * 32 + t] = s2;
  } else if (t < 35) {
    float s = 0.f;
    if (t == 32) { for (int r = 0; r < 16; ++r) s += sVec[r]; }
    if (t == 33) { for (int r = 0; r < 16; ++r) s += sVec[r] * sMc[r]; }
    if (t == 34) { for (int r = 0; r < 16; ++r) s += sVec[r] * sDg[r]; }
    pS[((size_t)b * 32 + ch) * 3 + (t - 32)] = s;
  }
}

// ---------------- K5: GEMM + in-block colv finalize + fused epilogue. grid (NB,16) ----------------
__global__ __launch_bounds__(512) void k5_mfma(
    const float* __restrict__ A, const unsigned short* __restrict__ Yext,
    const float* __restrict__ X, const float* __restrict__ W1,
    const float* __restrict__ W2, const float* __restrict__ vec,
    const float* __restrict__ mc, const float* __restrict__ dg,
    const float* __restrict__ pA, const float* __restrict__ pD,
    const float* __restrict__ pmX, const float* __restrict__ ptC,
    const float* __restrict__ pS, const float* __restrict__ cf,
    float* __restrict__ out) {
  int b = blockIdx.x, ic = blockIdx.y;
  int t = threadIdx.x, w = t >> 6, lane = t & 63;
  int ia = w & 1, q = w >> 1;
  int ra = lane & 15, kg = lane >> 4, g = lane >> 4;
  int i0 = ic * 32;
  __shared__ __align__(16) float sAcc[4 * 32 * 68];
  __shared__ float sG[4 * 32 * 2];
  __shared__ float sW1[64][69], sW2[64][69];
  __shared__ float smX[32], stC[32], sScal[8], sCf[69];
  __shared__ __align__(16) float sColv[64 * 8];

  // stage W1/W2 (all threads) — used by phase B after barrier
  for (int idx = t; idx < 64 * XN; idx += 512) {
    int r = idx / XN, c = idx - r * XN;
    sW1[r][c] = W1[idx];
    sW2[r][c] = W2[idx];
  }
  if (t < 69) sCf[t] = cf[t];
  // phase A (wave 0): reduce per-chunk partials
  if (t < 32) {
    float s1 = 0.f, s2 = 0.f;
#pragma unroll
    for (int k = 0; k < 32; ++k) {
      s1 += pmX[((size_t)b * 32 + k) * 32 + t];
      s2 += ptC[((size_t)b * 32 + k) * 32 + t];
    }
    smX[t] = s1 * (1.0f / NN);
    stC[t] = s2;
  } else if (t == 32) {
    float sA = 0.f, sD = 0.f;
#pragma unroll
    for (int k = 0; k < 32; ++k) { sA += pA[b * 32 + k]; sD += pD[b * 32 + k]; }
    sScal[0] = sD * (1.0f / NN);
    sScal[1] = sA * (1.0f / ((float)NN * (float)NN));
  } else if (t == 33) {
    float s1 = 0.f, s2 = 0.f, s3 = 0.f;
#pragma unroll
    for (int k = 0; k < 32; ++k) {
      s1 += pS[((size_t)b * 32 + k) * 3 + 0];
      s2 += pS[((size_t)b * 32 + k) * 3 + 1];
      s3 += pS[((size_t)b * 32 + k) * 3 + 2];
    }
    sScal[2] = s1; sScal[3] = s2; sScal[4] = s3;
  }
  __syncthreads();  // sW1/sW2/sCf staged; phase A visible

  float c0n = sCf[0] * (1.0f / NN);
  const float* Arow = A + ((size_t)(b * NN + i0 + ia * 16 + ra)) * NN;
  const unsigned short* Yb = Yext + (size_t)b * YR * NN;

  f32x4 acc[4] = {{0.f, 0.f, 0.f, 0.f}, {0.f, 0.f, 0.f, 0.f},
                  {0.f, 0.f, 0.f, 0.f}, {0.f, 0.f, 0.f, 0.f}};
  f32x4 acc4 = {0.f, 0.f, 0.f, 0.f};

#pragma unroll
  for (int jt = 0; jt < 4; ++jt) {
    int kb = q * 128 + jt * 32 + kg * 8;
    float4 a0 = *(const float4*)(Arow + kb);
    float4 a1 = *(const float4*)(Arow + kb + 4);
    bf16x8 af = cvt8s(a0, a1, c0n);
#pragma unroll
    for (int to = 0; to < 4; ++to) {
      bf16x8 bf = *(const bf16x8*)(Yb + (size_t)(to * 16 + ra) * NN + kb);
      acc[to] = __builtin_amdgcn_mfma_f32_16x16x32_bf16(af, bf, acc[to], 0, 0, 0);
    }
    bf16x8 bf4 = *(const bf16x8*)(Yb + (size_t)(64 + ra) * NN + kb);
    acc4 = __builtin_amdgcn_mfma_f32_16x16x32_bf16(af, bf4, acc4, 0, 0, 0);
  }

  if (q == 0) {  // fused X*W2c k-step (unscaled)
    const float* xp = X + (size_t)(b * NN + i0 + ia * 16 + ra) * CI + kg * 8;
    bf16x8 xf = cvt8(*(const float4*)xp, *(const float4*)(xp + 4));
#pragma unroll
    for (int to = 0; to < 4; ++to) {
      const float* wp = W2 + (size_t)(to * 16 + ra) * XN + kg * 8;
      bf16x8 wf = cvt8(*(const float4*)wp, *(const float4*)(wp + 4));
      acc[to] = __builtin_amdgcn_mfma_f32_16x16x32_bf16(xf, wf, acc[to], 0, 0, 0);
    }
  }

  // epilogue prefetch (global) before LDS store + barrier
  int ei = t >> 4, eo4 = (t & 15) * 4;
  float e_vc = vec[b * NN + i0 + ei];
  float e_mc = mc[b * NN + i0 + ei];
  float e_dg = dg[b * NN + i0 + ei];

#pragma unroll
  for (int to = 0; to < 4; ++to)
#pragma unroll
    for (int r = 0; r < 4; ++r)
      sAcc[(q * 32 + ia * 16 + g * 4 + r) * 68 + to * 16 + ra] = acc[to][r];
  if (ra < 2) {
#pragma unroll
    for (int r = 0; r < 4; ++r)
      sG[((q * 32 + ia * 16 + g * 4 + r) << 1) | ra] = acc4[r];
  }

  // phase B (wave 0, before the barrier — other waves are arriving anyway):
  // finalize colv from smX/stC/sScal + staged W1/W2
  if (t < CO) {
    int o = t;
    float w1mX = 0.f, a1 = 0.f, a2 = 0.f, wt = 0.f;
#pragma unroll
    for (int c = 0; c < CI; ++c) {
      float m = smX[c];
      w1mX += sW1[o][c] * m;
      a1 += sW1[o][CI + c] * m;
      a2 += sW2[o][CI + c] * m;
      wt += sW1[o][c] * stC[c];
    }
    float smd = sScal[0], sma = sScal[1];
    a1 += sW1[o][66] * smd + sW1[o][67] * sma;
    a2 += sW2[o][66] * smd + sW2[o][67] * sma;
    float we0 = sW1[o][64], we1 = sW1[o][65];
    float S1n = w1mX + a1 + we0 * sma + we1 * smd;
    float SVn = (wt + a1 * sScal[2] + we0 * sScal[3] + we1 * sScal[4]) * (1.0f / NN);
    sColv[o * 8 + 0] = S1n;
    sColv[o * 8 + 1] = a2 + SVn;
    sColv[o * 8 + 2] = sW2[o][64] + sCf[0] * a1;
    sColv[o * 8 + 3] = sW2[o][65];
    sColv[o * 8 + 4] = we0;
    sColv[o * 8 + 5] = we1;
  }
  if (t == 0) {
    float s7 = 0.f;
#pragma unroll
    for (int c = 0; c < CI; ++c) s7 += sCf[5 + CI + c] * smX[c];
    sScal[5] = sCf[1] * sScal[1] + sCf[2] * sScal[0] + s7;
  }
  __syncthreads();

  {
    float e_vp = e_vc + sScal[5];
    f32x4 s = {0.f, 0.f, 0.f, 0.f};
    float Gm = 0.f, Gd = 0.f;
#pragma unroll
    for (int qq = 0; qq < 4; ++qq) {
      s += *(const f32x4*)&sAcc[(qq * 32 + ei) * 68 + eo4];
      Gm += sG[((qq * 32 + ei) << 1)];
      Gd += sG[((qq * 32 + ei) << 1) | 1];
    }
    float4 res;
#pragma unroll
    for (int k = 0; k < 4; ++k) {
      int o = eo4 + k;
      float4 cva = *(const float4*)&sColv[o * 8];
      float vb0 = sColv[o * 8 + 4], vb1 = sColv[o * 8 + 5];
      float r = s[k] + e_vp * cva.x + cva.y + e_mc * cva.z + e_dg * cva.w +
                Gm * vb0 + Gd * vb1;
      (&res.x)[k] = r;
    }
    *(float4*)&out[((size_t)(b * NN + i0 + ei)) * CO + eo4] = res;
  }
}

extern "C" void kernel_launch(void* const* d_in, const int* in_sizes, int n_in,
                              void* d_out, int out_size, void* d_ws, size_t ws_size,
                              hipStream_t stream) {
  const float* A = (const float*)d_in[0];
  const float* X = (const float*)d_in[1];
  const float* cf = (const float*)d_in[2];
  const float* W1 = (const float*)d_in[3];
  const float* W2 = (const float*)d_in[4];
  float* out = (float*)d_out;

  float* p = (float*)d_ws;
  float* mc = p;      p += NB * NN;
  float* dg = p;      p += NB * NN;
  float* vec = p;     p += NB * NN;
  float* pA = p;      p += NB * 32;
  float* pD = p;      p += NB * 32;
  float* pmX = p;     p += NB * 32 * 32;
  float* ptC = p;     p += NB * 32 * 32;
  float* pS = p;      p += NB * 32 * 3;
  unsigned short* Yext = (unsigned short*)p;

  k1x<<<dim3(NB, 32), 256, 0, stream>>>(A, X, cf, W1, mc, dg, vec,
                                        pA, pD, pmX, ptC, pS, Yext);
  k5_mfma<<<dim3(NB, 16), 512, 0, stream>>>(A, Yext, X, W1, W2, vec, mc, dg,
                                            pA, pD, pmX, ptC, pS, cf, out);
}

// Round 9
// 54.585 us; speedup vs baseline: 1.1742x; 1.1742x over previous
//
#include <hip/hip_runtime.h>
#include <hip/hip_bf16.h>

#define NB 64
#define NN 512
#define CI 32
#define CO 64
#define XN 68
#define YR 80   // Yext rows per batch: 64 Y + mc + dg + 14 zero-pad

typedef __attribute__((ext_vector_type(8))) short bf16x8;
typedef __attribute__((ext_vector_type(4))) float f32x4;

__device__ inline short f2bf(float f) {
  union { __hip_bfloat16 h; unsigned short u; } cv;
  cv.h = __float2bfloat16(f);
  return (short)cv.u;
}

__device__ inline bf16x8 cvt8(float4 a, float4 b) {
  bf16x8 r;
  r[0] = f2bf(a.x); r[1] = f2bf(a.y); r[2] = f2bf(a.z); r[3] = f2bf(a.w);
  r[4] = f2bf(b.x); r[5] = f2bf(b.y); r[6] = f2bf(b.z); r[7] = f2bf(b.w);
  return r;
}

__device__ inline bf16x8 cvt8s(float4 a, float4 b, float s) {
  bf16x8 r;
  r[0] = f2bf(a.x * s); r[1] = f2bf(a.y * s); r[2] = f2bf(a.z * s); r[3] = f2bf(a.w * s);
  r[4] = f2bf(b.x * s); r[5] = f2bf(b.y * s); r[6] = f2bf(b.z * s); r[7] = f2bf(b.w * s);
  return r;
}

// ---------------- K1X: A row stats + X stats + Y-chunk (bf16 MFMA). grid (NB,32) ----------------
__global__ __launch_bounds__(256) void k1x(
    const float* __restrict__ A, const float* __restrict__ X,
    const float* __restrict__ cf, const float* __restrict__ W1,
    float* __restrict__ mc, float* __restrict__ dg, float* __restrict__ vec,
    float* __restrict__ pA, float* __restrict__ pD,
    float* __restrict__ pmX, float* __restrict__ ptC, float* __restrict__ pS,
    unsigned short* __restrict__ Yext) {
  int b = blockIdx.x, ch = blockIdx.y;
  int t = threadIdx.x, w = t >> 6, lane = t & 63;
  int r0 = ch * 16;
  const float* Ab = A + (size_t)b * NN * NN;
  __shared__ float sXc[16][33];
  __shared__ float scf[69];
  __shared__ float sMc[16], sDg[16], sVec[16], wsum[4];

  if (t < 69) scf[t] = cf[t];
  {  // stage X chunk: 16 rows x 32 cols
    int j = t >> 4, c = (t & 15) * 2;
    float2 xv = *(const float2*)(X + ((size_t)b * NN + r0 + j) * CI + c);
    sXc[j][c] = xv.x; sXc[j][c + 1] = xv.y;
  }
  float4 v0[4], v1[4];
#pragma unroll
  for (int m = 0; m < 4; ++m) {
    const float* rp = Ab + (size_t)(r0 + w * 4 + m) * NN;
    v0[m] = *(const float4*)(rp + lane * 4);
    v1[m] = *(const float4*)(rp + 256 + lane * 4);
  }
  float accR = 0.f;
#pragma unroll
  for (int m = 0; m < 4; ++m) {
    float s = (v0[m].x + v0[m].y) + (v0[m].z + v0[m].w) +
              (v1[m].x + v1[m].y) + (v1[m].z + v1[m].w);
#pragma unroll
    for (int off = 1; off < 64; off <<= 1) s += __shfl_xor(s, off, 64);
    if (lane == 0) {
      float m_ = s * (1.0f / NN);
      mc[b * NN + r0 + w * 4 + m] = m_;
      sMc[w * 4 + m] = m_;
    }
    accR += s;
  }
  if (lane == 0) wsum[w] = accR;
  if (t < 16) {
    float d = Ab[(size_t)(r0 + t) * NN + r0 + t];
    dg[b * NN + r0 + t] = d;
    sDg[t] = d;
  }
  __syncthreads();  // sXc, sMc, sDg, wsum, scf ready

  if (t < 16) {  // vec for this chunk's 16 rows
    float u = 0.f;
#pragma unroll
    for (int c = 0; c < CI; ++c) u += scf[5 + c] * sXc[t][c];
    float vj = scf[3] * sMc[t] + scf[4] * sDg[t] + u;
    vec[b * NN + r0 + t] = vj;
    sVec[t] = vj;
  } else if (t == 16) {
    pA[b * 32 + ch] = wsum[0] + wsum[1] + wsum[2] + wsum[3];
    float sd = 0.f;
#pragma unroll
    for (int k = 0; k < 16; ++k) sd += sDg[k];
    pD[b * 32 + ch] = sd;
  }

  {  // Y chunk via MFMA: wave w -> output rows o = w*16..w*16+15, cols r0..r0+15
    int ra = lane & 15, kg = lane >> 4, g = lane >> 4;
    const float* wp = W1 + (w * 16 + ra) * XN + kg * 8;
    bf16x8 wf = cvt8(*(const float4*)wp, *(const float4*)(wp + 4));
    const float* xp = &sXc[ra][kg * 8];
    bf16x8 xf = cvt8(*(const float4*)xp, *(const float4*)(xp + 4));
    f32x4 zero = {0.f, 0.f, 0.f, 0.f};
    f32x4 d = __builtin_amdgcn_mfma_f32_16x16x32_bf16(xf, wf, zero, 0, 0, 0);
    union { unsigned short u[4]; uint2 v; } pk;
#pragma unroll
    for (int r = 0; r < 4; ++r) pk.u[r] = (unsigned short)f2bf(d[r]);
    *(uint2*)(Yext + ((size_t)b * YR + w * 16 + ra) * NN + r0 + g * 4) = pk.v;
  }
  // Yext rows 64 (mc), 65 (dg) + zero pads 66..79, this chunk's 16 cols
  if (t < 16) {
    Yext[((size_t)b * YR + 64) * NN + r0 + t] = (unsigned short)f2bf(sMc[t]);
  } else if (t < 32) {
    Yext[((size_t)b * YR + 65) * NN + r0 + (t - 16)] = (unsigned short)f2bf(sDg[t - 16]);
  } else if (t < 32 + 224) {
    int u2 = t - 32;
    int row = 66 + (u2 >> 4), col = r0 + (u2 & 15);
    Yext[((size_t)b * YR + row) * NN + col] = 0;
  }
  __syncthreads();  // sVec ready

  if (t < 32) {  // column partials over this chunk
    float s1 = 0.f, s2 = 0.f;
#pragma unroll
    for (int r = 0; r < 16; ++r) {
      float xv = sXc[r][t];
      s1 += xv;
      s2 += sVec[r] * xv;
    }
    pmX[((size_t)b * 32 + ch) * 32 + t] = s1;
    ptC[((size_t)b * 32 + ch) * 32 + t] = s2;
  } else if (t < 35) {
    float s = 0.f;
    if (t == 32) { for (int r = 0; r < 16; ++r) s += sVec[r]; }
    if (t == 33) { for (int r = 0; r < 16; ++r) s += sVec[r] * sMc[r]; }
    if (t == 34) { for (int r = 0; r < 16; ++r) s += sVec[r] * sDg[r]; }
    pS[((size_t)b * 32 + ch) * 3 + (t - 32)] = s;
  }
}

// ---------------- KW: finalize stats -> colv, sconst. grid (16) ----------------
__global__ __launch_bounds__(256) void kW(
    const float* __restrict__ cf, const float* __restrict__ W1,
    const float* __restrict__ W2, const float* __restrict__ pA,
    const float* __restrict__ pD, const float* __restrict__ pmX,
    const float* __restrict__ ptC, const float* __restrict__ pS,
    float* __restrict__ colv, float* __restrict__ sconst) {
  int gb = blockIdx.x, t = threadIdx.x;
  int bb0 = gb * 4;
  __shared__ float sW1[64][69], sW2[64][69];
  __shared__ float mXs[4][33], tCs[4][33];
  __shared__ float scal[4][6];
  __shared__ float scf[69];
  if (t < 69) scf[t] = cf[t];
  for (int idx = t; idx < 64 * XN; idx += 256) {
    int r = idx / XN, c = idx - r * XN;
    sW1[r][c] = W1[idx];
    sW2[r][c] = W2[idx];
  }
  if (t < 128) {
    int bb = t >> 5, c = t & 31, b = bb0 + bb;
    float s1 = 0.f, s2 = 0.f;
#pragma unroll
    for (int k = 0; k < 32; ++k) {
      s1 += pmX[((size_t)b * 32 + k) * 32 + c];
      s2 += ptC[((size_t)b * 32 + k) * 32 + c];
    }
    mXs[bb][c] = s1 * (1.0f / NN);
    tCs[bb][c] = s2;
  } else if (t < 132) {
    int bb = t - 128, b = bb0 + bb;
    float sA = 0.f, sD = 0.f;
#pragma unroll
    for (int k = 0; k < 32; ++k) { sA += pA[b * 32 + k]; sD += pD[b * 32 + k]; }
    scal[bb][0] = sD * (1.0f / NN);
    scal[bb][1] = sA * (1.0f / ((float)NN * (float)NN));
  } else if (t < 136) {
    int bb = t - 132, b = bb0 + bb;
    float s1 = 0.f, s2 = 0.f, s3 = 0.f;
#pragma unroll
    for (int k = 0; k < 32; ++k) {
      s1 += pS[((size_t)b * 32 + k) * 3 + 0];
      s2 += pS[((size_t)b * 32 + k) * 3 + 1];
      s3 += pS[((size_t)b * 32 + k) * 3 + 2];
    }
    scal[bb][2] = s1; scal[bb][3] = s2; scal[bb][4] = s3;
  }
  __syncthreads();
  if (t < 4) {
    float s7 = 0.f;
#pragma unroll
    for (int c = 0; c < CI; ++c) s7 += scf[5 + CI + c] * mXs[t][c];
    sconst[bb0 + t] = scf[1] * scal[t][1] + scf[2] * scal[t][0] + s7;
  }
  {
    int bb = t >> 6, o = t & 63, b = bb0 + bb;
    float w1mX = 0.f, a1 = 0.f, a2 = 0.f, wt = 0.f;
#pragma unroll
    for (int c = 0; c < CI; ++c) {
      float m = mXs[bb][c];
      w1mX += sW1[o][c] * m;
      a1 += sW1[o][CI + c] * m;
      a2 += sW2[o][CI + c] * m;
      wt += sW1[o][c] * tCs[bb][c];
    }
    float smd = scal[bb][0], sma = scal[bb][1];
    a1 += sW1[o][66] * smd + sW1[o][67] * sma;
    a2 += sW2[o][66] * smd + sW2[o][67] * sma;
    float we0 = sW1[o][64], we1 = sW1[o][65];
    float S1n = w1mX + a1 + we0 * sma + we1 * smd;
    float SVn = (wt + a1 * scal[bb][2] + we0 * scal[bb][3] + we1 * scal[bb][4]) * (1.0f / NN);
    float4 cva = make_float4(S1n, a2 + SVn, sW2[o][64] + scf[0] * a1, sW2[o][65]);
    float4 cvb = make_float4(we0, we1, 0.f, 0.f);
    *(float4*)&colv[((size_t)b * CO + o) * 8] = cva;
    *(float4*)&colv[((size_t)b * CO + o) * 8 + 4] = cvb;
  }
}

// ---------------- K5: streaming MFMA GEMM, full-K per wave, no LDS, no barrier ----------------
// grid (NB, 8), 256 threads = 4 waves; wave w owns rows i0 = ic*64 + w*16 .. +16.
__global__ __launch_bounds__(256) void k5_mfma(
    const float* __restrict__ A, const unsigned short* __restrict__ Yext,
    const float* __restrict__ X, const float* __restrict__ W2,
    const float* __restrict__ vec, const float* __restrict__ mc,
    const float* __restrict__ dg, const float* __restrict__ colv,
    const float* __restrict__ sconst, const float* __restrict__ cf,
    float* __restrict__ out) {
  int b = blockIdx.x, ic = blockIdx.y;
  int t = threadIdx.x, w = t >> 6, lane = t & 63;
  int ra = lane & 15, kg = lane >> 4, g = lane >> 4;
  int i0 = ic * 64 + w * 16;

  float c0n = cf[0] * (1.0f / NN);
  const float* Arow = A + ((size_t)(b * NN + i0 + ra)) * NN;
  const unsigned short* Yb = Yext + (size_t)b * YR * NN;

  f32x4 acc[4] = {{0.f, 0.f, 0.f, 0.f}, {0.f, 0.f, 0.f, 0.f},
                  {0.f, 0.f, 0.f, 0.f}, {0.f, 0.f, 0.f, 0.f}};
  f32x4 acc4 = {0.f, 0.f, 0.f, 0.f};

#pragma unroll
  for (int jt = 0; jt < 16; ++jt) {
    int kb = jt * 32 + kg * 8;
    float4 a0 = *(const float4*)(Arow + kb);
    float4 a1 = *(const float4*)(Arow + kb + 4);
    bf16x8 af = cvt8s(a0, a1, c0n);
#pragma unroll
    for (int to = 0; to < 4; ++to) {
      bf16x8 bf = *(const bf16x8*)(Yb + (size_t)(to * 16 + ra) * NN + kb);
      acc[to] = __builtin_amdgcn_mfma_f32_16x16x32_bf16(af, bf, acc[to], 0, 0, 0);
    }
    bf16x8 bf4 = *(const bf16x8*)(Yb + (size_t)(64 + ra) * NN + kb);
    acc4 = __builtin_amdgcn_mfma_f32_16x16x32_bf16(af, bf4, acc4, 0, 0, 0);
  }

  {  // fused X*W2c k-step (unscaled) — every wave, its own 16 rows
    const float* xp = X + (size_t)(b * NN + i0 + ra) * CI + kg * 8;
    bf16x8 xf = cvt8(*(const float4*)xp, *(const float4*)(xp + 4));
#pragma unroll
    for (int to = 0; to < 4; ++to) {
      const float* wp = W2 + (size_t)(to * 16 + ra) * XN + kg * 8;
      bf16x8 wf = cvt8(*(const float4*)wp, *(const float4*)(wp + 4));
      acc[to] = __builtin_amdgcn_mfma_f32_16x16x32_bf16(xf, wf, acc[to], 0, 0, 0);
    }
  }

  // Gm/Gd live in lanes ra==0 / ra==1 of each g-group: broadcast via shuffle
  float Gm[4], Gd[4];
#pragma unroll
  for (int r = 0; r < 4; ++r) {
    Gm[r] = __shfl(acc4[r], lane & 48, 64);
    Gd[r] = __shfl(acc4[r], (lane & 48) | 1, 64);
  }

  // epilogue: rows i0+g*4..+3 (float4 row-vectors), cols to*16+ra
  float4 v4 = *(const float4*)&vec[b * NN + i0 + g * 4];
  float4 m4 = *(const float4*)&mc[b * NN + i0 + g * 4];
  float4 d4 = *(const float4*)&dg[b * NN + i0 + g * 4];
  float sc = sconst[b];
  float vp[4] = {v4.x + sc, v4.y + sc, v4.z + sc, v4.w + sc};
  float mr[4] = {m4.x, m4.y, m4.z, m4.w};
  float dr[4] = {d4.x, d4.y, d4.z, d4.w};

#pragma unroll
  for (int to = 0; to < 4; ++to) {
    int o = to * 16 + ra;
    float4 cva = *(const float4*)&colv[((size_t)b * CO + o) * 8];
    float4 cvb = *(const float4*)&colv[((size_t)b * CO + o) * 8 + 4];
#pragma unroll
    for (int r = 0; r < 4; ++r) {
      float val = acc[to][r] + vp[r] * cva.x + cva.y + mr[r] * cva.z +
                  dr[r] * cva.w + Gm[r] * cvb.x + Gd[r] * cvb.y;
      out[((size_t)(b * NN + i0 + g * 4 + r)) * CO + o] = val;
    }
  }
}

extern "C" void kernel_launch(void* const* d_in, const int* in_sizes, int n_in,
                              void* d_out, int out_size, void* d_ws, size_t ws_size,
                              hipStream_t stream) {
  const float* A = (const float*)d_in[0];
  const float* X = (const float*)d_in[1];
  const float* cf = (const float*)d_in[2];
  const float* W1 = (const float*)d_in[3];
  const float* W2 = (const float*)d_in[4];
  float* out = (float*)d_out;

  float* p = (float*)d_ws;
  float* mc = p;      p += NB * NN;
  float* dg = p;      p += NB * NN;
  float* vec = p;     p += NB * NN;
  float* pA = p;      p += NB * 32;
  float* pD = p;      p += NB * 32;
  float* pmX = p;     p += NB * 32 * 32;
  float* ptC = p;     p += NB * 32 * 32;
  float* pS = p;      p += NB * 32 * 3;
  float* colv = p;    p += NB * CO * 8;
  float* sconst = p;  p += NB;
  unsigned short* Yext = (unsigned short*)p;

  k1x<<<dim3(NB, 32), 256, 0, stream>>>(A, X, cf, W1, mc, dg, vec,
                                        pA, pD, pmX, ptC, pS, Yext);
  kW<<<16, 256, 0, stream>>>(cf, W1, W2, pA, pD, pmX, ptC, pS, colv, sconst);
  k5_mfma<<<dim3(NB, 8), 256, 0, stream>>>(A, Yext, X, W2, vec, mc, dg,
                                           colv, sconst, cf, out);
}